// Round 1
// baseline (663.186 us; speedup 1.0000x reference)
//
#include <hip/hip_runtime.h>
#include <cmath>

typedef __bf16 bf16;
typedef __bf16 bf16x8 __attribute__((ext_vector_type(8)));
typedef __bf16 bf16x4 __attribute__((ext_vector_type(4)));
typedef float f32x4 __attribute__((ext_vector_type(4)));

#define MAXNORM 0.99999f      // (1-EPS)/sqrt(C), C=1, EPS=1e-5
#define ATH_CLIP 0.9999999f   // 1-1e-7 artanh clip
#define MINN 1e-15f

// async global->LDS, 16B per lane. LDS dest is wave-uniform base + lane*16,
// so per-lane lds ptrs MUST be contiguous in lane order (they are: t*16B).
__device__ __forceinline__ void g2l16(const void* g, void* l) {
  __builtin_amdgcn_global_load_lds(
      (const __attribute__((address_space(1))) void*)g,
      (__attribute__((address_space(3))) void*)l, 16, 0, 0);
}

// block-wide (256 thr) sum-reduce of two floats; result broadcast to all threads
__device__ __forceinline__ void reduce2(float& a, float& b) {
  __shared__ float sr[8];
  #pragma unroll
  for (int off = 32; off > 0; off >>= 1) {
    a += __shfl_down(a, off, 64);
    b += __shfl_down(b, off, 64);
  }
  int w = threadIdx.x >> 6;
  if ((threadIdx.x & 63) == 0) { sr[w] = a; sr[4 + w] = b; }
  __syncthreads();
  a = sr[0] + sr[1] + sr[2] + sr[3];
  b = sr[4] + sr[5] + sr[6] + sr[7];
  __syncthreads();
}

// y = expmap0(bias) = tanh(|b|)/|b| * b ; y2 = |y|^2
__global__ __launch_bounds__(256) void prep_bias(const float* __restrict__ b,
                                                 float* __restrict__ y,
                                                 float* __restrict__ y2, int n) {
  int t = threadIdx.x;
  int n4 = n >> 2;
  float ss = 0.f;
  for (int i = t; i < n4; i += 256) {
    float4 v = ((const float4*)b)[i];
    ss += v.x * v.x + v.y * v.y + v.z * v.z + v.w * v.w;
  }
  float d = 0.f;
  reduce2(ss, d);
  float un = fmaxf(sqrtf(ss), MINN);
  float sc = tanhf(un) / un;
  for (int i = t; i < n4; i += 256) {
    float4 v = ((const float4*)b)[i];
    float4 o;
    o.x = v.x * sc; o.y = v.y * sc; o.z = v.z * sc; o.w = v.w * sc;
    ((float4*)y)[i] = o;
  }
  if (t == 0) *y2 = sc * sc * ss;
}

// W fp32 -> bf16, 8 elems/thread
__global__ __launch_bounds__(256) void conv_w(const float* __restrict__ W,
                                              bf16* __restrict__ Wb, long n) {
  long i = ((long)blockIdx.x * 256 + threadIdx.x) * 8;
  if (i + 8 <= n) {
    float4 a = *(const float4*)(W + i);
    float4 b = *(const float4*)(W + i + 4);
    bf16x8 o;
    o[0] = (bf16)a.x; o[1] = (bf16)a.y; o[2] = (bf16)a.z; o[3] = (bf16)a.w;
    o[4] = (bf16)b.x; o[5] = (bf16)b.y; o[6] = (bf16)b.z; o[7] = (bf16)b.w;
    *(bf16x8*)(Wb + i) = o;
  }
}

// per-row: project x into ball, cast->bf16, store q = artanh(xn)/xn
// hardcoded for IN == 4096 (16 elems / thread)
__global__ __launch_bounds__(256) void prep_x(const float* __restrict__ x,
                                              bf16* __restrict__ xb,
                                              float* __restrict__ q, int IN) {
  int row = blockIdx.x, t = threadIdx.x;
  const float4* xr = (const float4*)(x + (size_t)row * IN);
  float4 v[4];
  float ss = 0.f;
  #pragma unroll
  for (int ii = 0; ii < 4; ii++) {
    float4 a = xr[ii * 256 + t];
    v[ii] = a;
    ss += a.x * a.x + a.y * a.y + a.z * a.z + a.w * a.w;
  }
  float d = 0.f;
  reduce2(ss, d);
  float nrm = sqrtf(ss);
  float s = 1.f, xn = fmaxf(nrm, MINN);
  if (nrm > MAXNORM) { s = MAXNORM / nrm; xn = MAXNORM; }
  if (t == 0) q[row] = atanhf(fminf(xn, ATH_CLIP)) / xn;
  bf16* xo = xb + (size_t)row * IN;
  #pragma unroll
  for (int ii = 0; ii < 4; ii++) {
    float4 a = v[ii];
    bf16x4 o;
    o[0] = (bf16)(a.x * s); o[1] = (bf16)(a.y * s);
    o[2] = (bf16)(a.z * s); o[3] = (bf16)(a.w * s);
    *(bf16x4*)(xo + (size_t)(ii * 256 + t) * 4) = o;
  }
}

// C[m,n] = sum_k A[m,k]*B[n,k]; A:[M,K] bf16 row-major, B:[N,K] bf16 row-major
// 128x128 tile / block (4 waves, each 64x64 via 4x4 of 16x16x32 MFMA), BK=32
__global__ __launch_bounds__(256) void gemm_bt(const bf16* __restrict__ A,
                                               const bf16* __restrict__ B,
                                               float* __restrict__ C, int K,
                                               int N) {
  __shared__ __align__(16) bf16 sA[128 * 32];
  __shared__ __align__(16) bf16 sB[128 * 32];
  int t = threadIdx.x;
  int m0 = blockIdx.y * 128, n0 = blockIdx.x * 128;
  const bf16* Ag = A + (size_t)(m0 + (t >> 2)) * K + (t & 3) * 8;
  const bf16* Bg = B + (size_t)(n0 + (t >> 2)) * K + (t & 3) * 8;
  bf16* lA = sA + t * 8;
  bf16* lB = sB + t * 8;
  size_t rstep = (size_t)64 * K;

  int lane = t & 63, w = t >> 6;
  int quad = lane >> 4, lrow = lane & 15;
  int wm = (w >> 1) * 64, wn = (w & 1) * 64;
  const bf16* pA[4];
  const bf16* pB[4];
  #pragma unroll
  for (int i = 0; i < 4; i++) {
    pA[i] = sA + (wm + i * 16 + lrow) * 32 + quad * 8;
    pB[i] = sB + (wn + i * 16 + lrow) * 32 + quad * 8;
  }
  f32x4 acc[4][4];
  #pragma unroll
  for (int i = 0; i < 4; i++)
    #pragma unroll
    for (int j = 0; j < 4; j++) acc[i][j] = (f32x4)0.f;

  for (int k0 = 0; k0 < K; k0 += 32) {
    g2l16(Ag + k0, lA);
    g2l16(Ag + rstep + k0, lA + 256 * 8);
    g2l16(Bg + k0, lB);
    g2l16(Bg + rstep + k0, lB + 256 * 8);
    __syncthreads();  // waits vmcnt(0) -> staging complete
    bf16x8 af[4], bfr[4];
    #pragma unroll
    for (int i = 0; i < 4; i++) af[i] = *(const bf16x8*)pA[i];
    #pragma unroll
    for (int j = 0; j < 4; j++) bfr[j] = *(const bf16x8*)pB[j];
    #pragma unroll
    for (int i = 0; i < 4; i++)
      #pragma unroll
      for (int j = 0; j < 4; j++)
        acc[i][j] =
            __builtin_amdgcn_mfma_f32_16x16x32_bf16(af[i], bfr[j], acc[i][j], 0, 0, 0);
    __syncthreads();
  }
  // C/D layout: n = lane&15, m = quad*4 + reg (m89/m91-verified mapping)
  #pragma unroll
  for (int i = 0; i < 4; i++) {
    #pragma unroll
    for (int r = 0; r < 4; r++) {
      int row = m0 + wm + i * 16 + quad * 4 + r;
      float* Cr = C + (size_t)row * N + n0 + wn + lrow;
      #pragma unroll
      for (int j = 0; j < 4; j++) Cr[j * 16] = acc[i][j][r];
    }
  }
}

// per-row: Smm=sum mx^2, Smy=sum mx*y -> scalars -> out = s*(A*mx + B*y)
// in-place on d_out. hardcoded for N == 4096.
__global__ __launch_bounds__(256) void finish(float* __restrict__ out,
                                              const float* __restrict__ y,
                                              const float* __restrict__ y2p,
                                              const float* __restrict__ q,
                                              int N) {
  int row = blockIdx.x, t = threadIdx.x;
  float4* orow = (float4*)(out + (size_t)row * N);
  const float4* yv = (const float4*)y;
  float smm = 0.f, smy = 0.f;
  float4 rm[4], ry[4];
  #pragma unroll
  for (int ii = 0; ii < 4; ii++) {
    float4 a = orow[ii * 256 + t];
    float4 b = yv[ii * 256 + t];
    rm[ii] = a;
    ry[ii] = b;
    smm += a.x * a.x + a.y * a.y + a.z * a.z + a.w * a.w;
    smy += a.x * b.x + a.y * b.y + a.z * b.z + a.w * b.w;
  }
  reduce2(smm, smy);
  float y2 = *y2p;  // = |y|^2
  float mxn = fmaxf(sqrtf(smm), MINN);
  float r = tanhf(mxn * q[row]);
  float alpha = (smm == 0.f) ? 0.f : r / mxn;  // res = alpha * mx
  float x2 = (smm == 0.f) ? 0.f : r * r;       // |res|^2
  float xy = alpha * smy;                      // <res, y>
  float c1 = 1.f + 2.f * xy + y2;
  float den = fmaxf(1.f + 2.f * xy + x2 * y2, MINN);
  float Af = c1 * alpha / den;
  float Bf = (1.f - x2) / den;
  // |o|^2 analytically: no second reduction needed
  float on2 = Af * Af * smm + 2.f * Af * Bf * smy + Bf * Bf * y2;
  float on = sqrtf(fmaxf(on2, 0.f));
  float s = (on > MAXNORM) ? MAXNORM / fmaxf(on, MINN) : 1.f;
  float As = Af * s, Bs = Bf * s;
  #pragma unroll
  for (int ii = 0; ii < 4; ii++) {
    float4 a = rm[ii], b = ry[ii];
    float4 o;
    o.x = As * a.x + Bs * b.x;
    o.y = As * a.y + Bs * b.y;
    o.z = As * a.z + Bs * b.z;
    o.w = As * a.w + Bs * b.w;
    orow[ii * 256 + t] = o;
  }
}

extern "C" void kernel_launch(void* const* d_in, const int* in_sizes, int n_in,
                              void* d_out, int out_size, void* d_ws,
                              size_t ws_size, hipStream_t stream) {
  const float* x = (const float*)d_in[0];
  const float* W = (const float*)d_in[1];
  const float* bias = (const float*)d_in[2];
  float* out = (float*)d_out;
  int OUT = in_sizes[2];
  int IN = in_sizes[1] / OUT;
  int Bm = in_sizes[0] / IN;

  // workspace carve: Xb (B*IN bf16) | Wb (OUT*IN bf16) | q (B f32) | y (OUT f32) | y2 (1 f32)
  char* ws = (char*)d_ws;
  size_t xb_bytes = (size_t)Bm * IN * sizeof(bf16);
  size_t wb_bytes = (size_t)OUT * IN * sizeof(bf16);
  bf16* Xb = (bf16*)ws;
  bf16* Wb = (bf16*)(ws + xb_bytes);
  float* q = (float*)(ws + xb_bytes + wb_bytes);
  float* y = q + Bm;
  float* y2 = y + OUT;

  prep_bias<<<1, 256, 0, stream>>>(bias, y, y2, OUT);
  conv_w<<<(int)(((size_t)OUT * IN / 8 + 255) / 256), 256, 0, stream>>>(
      W, Wb, (long)OUT * IN);
  prep_x<<<Bm, 256, 0, stream>>>(x, Xb, q, IN);
  gemm_bt<<<dim3(OUT / 128, Bm / 128), 256, 0, stream>>>(Xb, Wb, out, IN, OUT);
  finish<<<Bm, 256, 0, stream>>>(out, y, y2, q, OUT);
}

// Round 2
// 659.108 us; speedup vs baseline: 1.0062x; 1.0062x over previous
//
#include <hip/hip_runtime.h>
#include <cmath>

typedef __bf16 bf16;
typedef __bf16 bf16x8 __attribute__((ext_vector_type(8)));
typedef __bf16 bf16x4 __attribute__((ext_vector_type(4)));
typedef float f32x4 __attribute__((ext_vector_type(4)));

#define MAXNORM 0.99999f      // (1-EPS)/sqrt(C), C=1, EPS=1e-5
#define ATH_CLIP 0.9999999f   // 1-1e-7 artanh clip
#define MINN 1e-15f

// async global->LDS, 16B per lane. LDS dest is wave-uniform base + lane*16,
// so per-lane lds ptrs MUST be contiguous in lane order (they are: t*16B).
__device__ __forceinline__ void g2l16(const void* g, void* l) {
  __builtin_amdgcn_global_load_lds(
      (const __attribute__((address_space(1))) void*)g,
      (__attribute__((address_space(3))) void*)l, 16, 0, 0);
}

// block-wide (256 thr) sum-reduce of two floats; result broadcast to all threads
__device__ __forceinline__ void reduce2(float& a, float& b) {
  __shared__ float sr[8];
  #pragma unroll
  for (int off = 32; off > 0; off >>= 1) {
    a += __shfl_down(a, off, 64);
    b += __shfl_down(b, off, 64);
  }
  int w = threadIdx.x >> 6;
  if ((threadIdx.x & 63) == 0) { sr[w] = a; sr[4 + w] = b; }
  __syncthreads();
  a = sr[0] + sr[1] + sr[2] + sr[3];
  b = sr[4] + sr[5] + sr[6] + sr[7];
  __syncthreads();
}

// fused prep: [0, convBlocks) -> W cast, [convBlocks, convBlocks+Bm) -> x rows,
// last block -> bias expmap0. Branch is block-uniform (no divergence cost).
__global__ __launch_bounds__(256) void prep_all(
    const float* __restrict__ W, bf16* __restrict__ Wb, long nw, int convBlocks,
    const float* __restrict__ x, bf16* __restrict__ xb, float* __restrict__ q,
    int IN, int Bm, const float* __restrict__ bias, float* __restrict__ y,
    float* __restrict__ y2, int OUT) {
  int t = threadIdx.x;
  int b = blockIdx.x;
  if (b < convBlocks) {
    // ---- W fp32 -> bf16, 8 elems/thread ----
    long i = ((long)b * 256 + t) * 8;
    if (i + 8 <= nw) {
      float4 a = *(const float4*)(W + i);
      float4 c = *(const float4*)(W + i + 4);
      bf16x8 o;
      o[0] = (bf16)a.x; o[1] = (bf16)a.y; o[2] = (bf16)a.z; o[3] = (bf16)a.w;
      o[4] = (bf16)c.x; o[5] = (bf16)c.y; o[6] = (bf16)c.z; o[7] = (bf16)c.w;
      *(bf16x8*)(Wb + i) = o;
    }
  } else if (b < convBlocks + Bm) {
    // ---- per-row: project x, cast->bf16, q = artanh(xn)/xn (IN==4096) ----
    int row = b - convBlocks;
    const float4* xr = (const float4*)(x + (size_t)row * IN);
    float4 v[4];
    float ss = 0.f;
    #pragma unroll
    for (int ii = 0; ii < 4; ii++) {
      float4 a = xr[ii * 256 + t];
      v[ii] = a;
      ss += a.x * a.x + a.y * a.y + a.z * a.z + a.w * a.w;
    }
    float d = 0.f;
    reduce2(ss, d);
    float nrm = sqrtf(ss);
    float s = 1.f, xn = fmaxf(nrm, MINN);
    if (nrm > MAXNORM) { s = MAXNORM / nrm; xn = MAXNORM; }
    if (t == 0) q[row] = atanhf(fminf(xn, ATH_CLIP)) / xn;
    bf16* xo = xb + (size_t)row * IN;
    #pragma unroll
    for (int ii = 0; ii < 4; ii++) {
      float4 a = v[ii];
      bf16x4 o;
      o[0] = (bf16)(a.x * s); o[1] = (bf16)(a.y * s);
      o[2] = (bf16)(a.z * s); o[3] = (bf16)(a.w * s);
      *(bf16x4*)(xo + (size_t)(ii * 256 + t) * 4) = o;
    }
  } else {
    // ---- y = expmap0(bias), y2 = |y|^2 ----
    int n4 = OUT >> 2;
    float ss = 0.f;
    for (int i = t; i < n4; i += 256) {
      float4 v = ((const float4*)bias)[i];
      ss += v.x * v.x + v.y * v.y + v.z * v.z + v.w * v.w;
    }
    float d = 0.f;
    reduce2(ss, d);
    float un = fmaxf(sqrtf(ss), MINN);
    float sc = tanhf(un) / un;
    for (int i = t; i < n4; i += 256) {
      float4 v = ((const float4*)bias)[i];
      float4 o;
      o.x = v.x * sc; o.y = v.y * sc; o.z = v.z * sc; o.w = v.w * sc;
      ((float4*)y)[i] = o;
    }
    if (t == 0) *y2 = sc * sc * ss;
  }
}

// C[m,n] = sum_k A[m,k]*B[n,k]; A:[M,K] bf16 row-major, B:[N,K] bf16 row-major
// 128x128 tile / block (4 waves, each 64x64 via 4x4 of 16x16x32 MFMA), BK=32.
// LDS k-seg slots XOR-swizzled: (row r, kseg k) lives at slot r*4 + (k ^ ((r>>1)&3)).
// Staging picks the global source per lane (LDS dest forced to t*16B); reads
// then hit each 16B bank-group exactly 2x -> conflict-free (2-way is free, m136).
__global__ __launch_bounds__(256) void gemm_bt(const bf16* __restrict__ A,
                                               const bf16* __restrict__ B,
                                               float* __restrict__ C, int K,
                                               int N) {
  __shared__ __align__(16) bf16 sA[128 * 32];
  __shared__ __align__(16) bf16 sB[128 * 32];
  int t = threadIdx.x;
  int m0 = blockIdx.y * 128, n0 = blockIdx.x * 128;
  int kseg = (t & 3) ^ ((t >> 3) & 3);  // swizzled global k-segment for slot t
  const bf16* Ag = A + (size_t)(m0 + (t >> 2)) * K + kseg * 8;
  const bf16* Bg = B + (size_t)(n0 + (t >> 2)) * K + kseg * 8;
  bf16* lA = sA + t * 8;
  bf16* lB = sB + t * 8;
  size_t rstep = (size_t)64 * K;

  int lane = t & 63, w = t >> 6;
  int quad = lane >> 4, lrow = lane & 15;
  int wm = (w >> 1) * 64, wn = (w & 1) * 64;
  int swz = quad ^ ((lrow >> 1) & 3);  // de-swizzle on the read side
  const bf16* pA[4];
  const bf16* pB[4];
  #pragma unroll
  for (int i = 0; i < 4; i++) {
    pA[i] = sA + (wm + i * 16 + lrow) * 32 + swz * 8;
    pB[i] = sB + (wn + i * 16 + lrow) * 32 + swz * 8;
  }
  f32x4 acc[4][4];
  #pragma unroll
  for (int i = 0; i < 4; i++)
    #pragma unroll
    for (int j = 0; j < 4; j++) acc[i][j] = (f32x4)0.f;

  for (int k0 = 0; k0 < K; k0 += 32) {
    g2l16(Ag + k0, lA);
    g2l16(Ag + rstep + k0, lA + 256 * 8);
    g2l16(Bg + k0, lB);
    g2l16(Bg + rstep + k0, lB + 256 * 8);
    __syncthreads();  // waits vmcnt(0) -> staging complete
    bf16x8 af[4], bfr[4];
    #pragma unroll
    for (int i = 0; i < 4; i++) af[i] = *(const bf16x8*)pA[i];
    #pragma unroll
    for (int j = 0; j < 4; j++) bfr[j] = *(const bf16x8*)pB[j];
    #pragma unroll
    for (int i = 0; i < 4; i++)
      #pragma unroll
      for (int j = 0; j < 4; j++)
        acc[i][j] =
            __builtin_amdgcn_mfma_f32_16x16x32_bf16(af[i], bfr[j], acc[i][j], 0, 0, 0);
    __syncthreads();
  }
  // C/D layout: n = lane&15, m = quad*4 + reg (m89/m91-verified mapping)
  #pragma unroll
  for (int i = 0; i < 4; i++) {
    #pragma unroll
    for (int r = 0; r < 4; r++) {
      int row = m0 + wm + i * 16 + quad * 4 + r;
      float* Cr = C + (size_t)row * N + n0 + wn + lrow;
      #pragma unroll
      for (int j = 0; j < 4; j++) Cr[j * 16] = acc[i][j][r];
    }
  }
}

// per-row: Smm=sum mx^2, Smy=sum mx*y -> scalars -> out = s*(A*mx + B*y)
// in-place on d_out. hardcoded for N == 4096.
__global__ __launch_bounds__(256) void finish(float* __restrict__ out,
                                              const float* __restrict__ y,
                                              const float* __restrict__ y2p,
                                              const float* __restrict__ q,
                                              int N) {
  int row = blockIdx.x, t = threadIdx.x;
  float4* orow = (float4*)(out + (size_t)row * N);
  const float4* yv = (const float4*)y;
  float smm = 0.f, smy = 0.f;
  float4 rm[4], ry[4];
  #pragma unroll
  for (int ii = 0; ii < 4; ii++) {
    float4 a = orow[ii * 256 + t];
    float4 b = yv[ii * 256 + t];
    rm[ii] = a;
    ry[ii] = b;
    smm += a.x * a.x + a.y * a.y + a.z * a.z + a.w * a.w;
    smy += a.x * b.x + a.y * b.y + a.z * b.z + a.w * b.w;
  }
  reduce2(smm, smy);
  float y2 = *y2p;  // = |y|^2
  float mxn = fmaxf(sqrtf(smm), MINN);
  float r = tanhf(mxn * q[row]);
  float alpha = (smm == 0.f) ? 0.f : r / mxn;  // res = alpha * mx
  float x2 = (smm == 0.f) ? 0.f : r * r;       // |res|^2
  float xy = alpha * smy;                      // <res, y>
  float c1 = 1.f + 2.f * xy + y2;
  float den = fmaxf(1.f + 2.f * xy + x2 * y2, MINN);
  float Af = c1 * alpha / den;
  float Bf = (1.f - x2) / den;
  // |o|^2 analytically: no second reduction needed
  float on2 = Af * Af * smm + 2.f * Af * Bf * smy + Bf * Bf * y2;
  float on = sqrtf(fmaxf(on2, 0.f));
  float s = (on > MAXNORM) ? MAXNORM / fmaxf(on, MINN) : 1.f;
  float As = Af * s, Bs = Bf * s;
  #pragma unroll
  for (int ii = 0; ii < 4; ii++) {
    float4 a = rm[ii], b = ry[ii];
    float4 o;
    o.x = As * a.x + Bs * b.x;
    o.y = As * a.y + Bs * b.y;
    o.z = As * a.z + Bs * b.z;
    o.w = As * a.w + Bs * b.w;
    orow[ii * 256 + t] = o;
  }
}

extern "C" void kernel_launch(void* const* d_in, const int* in_sizes, int n_in,
                              void* d_out, int out_size, void* d_ws,
                              size_t ws_size, hipStream_t stream) {
  const float* x = (const float*)d_in[0];
  const float* W = (const float*)d_in[1];
  const float* bias = (const float*)d_in[2];
  float* out = (float*)d_out;
  int OUT = in_sizes[2];
  int IN = in_sizes[1] / OUT;
  int Bm = in_sizes[0] / IN;

  // workspace carve: Xb (B*IN bf16) | Wb (OUT*IN bf16) | q (B f32) | y (OUT f32) | y2 (1 f32)
  char* ws = (char*)d_ws;
  size_t xb_bytes = (size_t)Bm * IN * sizeof(bf16);
  size_t wb_bytes = (size_t)OUT * IN * sizeof(bf16);
  bf16* Xb = (bf16*)ws;
  bf16* Wb = (bf16*)(ws + xb_bytes);
  float* q = (float*)(ws + xb_bytes + wb_bytes);
  float* y = q + Bm;
  float* y2 = y + OUT;

  long nw = (long)OUT * IN;
  int convBlocks = (int)((nw / 8 + 255) / 256);
  prep_all<<<convBlocks + Bm + 1, 256, 0, stream>>>(
      W, Wb, nw, convBlocks, x, Xb, q, IN, Bm, bias, y, y2, OUT);
  gemm_bt<<<dim3(OUT / 128, Bm / 128), 256, 0, stream>>>(Xb, Wb, out, IN, OUT);
  finish<<<Bm, 256, 0, stream>>>(out, y, y2, q, OUT);
}

// Round 3
// 548.827 us; speedup vs baseline: 1.2084x; 1.2009x over previous
//
#include <hip/hip_runtime.h>
#include <cmath>

typedef __bf16 bf16;
typedef __bf16 bf16x8 __attribute__((ext_vector_type(8)));
typedef __bf16 bf16x4 __attribute__((ext_vector_type(4)));
typedef float f32x4 __attribute__((ext_vector_type(4)));

#define MAXNORM 0.99999f      // (1-EPS)/sqrt(C), C=1, EPS=1e-5
#define ATH_CLIP 0.9999999f   // 1-1e-7 artanh clip
#define MINN 1e-15f

// async global->LDS, 16B per lane. LDS dest is wave-uniform base + lane*16,
// so per-lane lds ptrs MUST be contiguous in lane order (they are: t*16B).
__device__ __forceinline__ void g2l16(const void* g, void* l) {
  __builtin_amdgcn_global_load_lds(
      (const __attribute__((address_space(1))) void*)g,
      (__attribute__((address_space(3))) void*)l, 16, 0, 0);
}

// block-wide (256 thr) sum-reduce of two floats; result broadcast to all threads
__device__ __forceinline__ void reduce2(float& a, float& b) {
  __shared__ float sr[8];
  #pragma unroll
  for (int off = 32; off > 0; off >>= 1) {
    a += __shfl_down(a, off, 64);
    b += __shfl_down(b, off, 64);
  }
  int w = threadIdx.x >> 6;
  if ((threadIdx.x & 63) == 0) { sr[w] = a; sr[4 + w] = b; }
  __syncthreads();
  a = sr[0] + sr[1] + sr[2] + sr[3];
  b = sr[4] + sr[5] + sr[6] + sr[7];
  __syncthreads();
}

// fused prep: [0, convBlocks) -> W cast, [convBlocks, convBlocks+Bm) -> x rows,
// last block -> bias expmap0. Branch is block-uniform (no divergence cost).
__global__ __launch_bounds__(256) void prep_all(
    const float* __restrict__ W, bf16* __restrict__ Wb, long nw, int convBlocks,
    const float* __restrict__ x, bf16* __restrict__ xb, float* __restrict__ q,
    int IN, int Bm, const float* __restrict__ bias, float* __restrict__ y,
    float* __restrict__ y2, int OUT) {
  int t = threadIdx.x;
  int b = blockIdx.x;
  if (b < convBlocks) {
    // ---- W fp32 -> bf16, 8 elems/thread ----
    long i = ((long)b * 256 + t) * 8;
    if (i + 8 <= nw) {
      float4 a = *(const float4*)(W + i);
      float4 c = *(const float4*)(W + i + 4);
      bf16x8 o;
      o[0] = (bf16)a.x; o[1] = (bf16)a.y; o[2] = (bf16)a.z; o[3] = (bf16)a.w;
      o[4] = (bf16)c.x; o[5] = (bf16)c.y; o[6] = (bf16)c.z; o[7] = (bf16)c.w;
      *(bf16x8*)(Wb + i) = o;
    }
  } else if (b < convBlocks + Bm) {
    // ---- per-row: project x, cast->bf16, q = artanh(xn)/xn (IN==4096) ----
    int row = b - convBlocks;
    const float4* xr = (const float4*)(x + (size_t)row * IN);
    float4 v[4];
    float ss = 0.f;
    #pragma unroll
    for (int ii = 0; ii < 4; ii++) {
      float4 a = xr[ii * 256 + t];
      v[ii] = a;
      ss += a.x * a.x + a.y * a.y + a.z * a.z + a.w * a.w;
    }
    float d = 0.f;
    reduce2(ss, d);
    float nrm = sqrtf(ss);
    float s = 1.f, xn = fmaxf(nrm, MINN);
    if (nrm > MAXNORM) { s = MAXNORM / nrm; xn = MAXNORM; }
    if (t == 0) q[row] = atanhf(fminf(xn, ATH_CLIP)) / xn;
    bf16* xo = xb + (size_t)row * IN;
    #pragma unroll
    for (int ii = 0; ii < 4; ii++) {
      float4 a = v[ii];
      bf16x4 o;
      o[0] = (bf16)(a.x * s); o[1] = (bf16)(a.y * s);
      o[2] = (bf16)(a.z * s); o[3] = (bf16)(a.w * s);
      *(bf16x4*)(xo + (size_t)(ii * 256 + t) * 4) = o;
    }
  } else {
    // ---- y = expmap0(bias), y2 = |y|^2 ----
    int n4 = OUT >> 2;
    float ss = 0.f;
    for (int i = t; i < n4; i += 256) {
      float4 v = ((const float4*)bias)[i];
      ss += v.x * v.x + v.y * v.y + v.z * v.z + v.w * v.w;
    }
    float d = 0.f;
    reduce2(ss, d);
    float un = fmaxf(sqrtf(ss), MINN);
    float sc = tanhf(un) / un;
    for (int i = t; i < n4; i += 256) {
      float4 v = ((const float4*)bias)[i];
      float4 o;
      o.x = v.x * sc; o.y = v.y * sc; o.z = v.z * sc; o.w = v.w * sc;
      ((float4*)y)[i] = o;
    }
    if (t == 0) *y2 = sc * sc * ss;
  }
}

// C[m,n] = sum_k A[m,k]*B[n,k]; A:[M,K] bf16 row-major, B:[N,K] bf16 row-major
// 128x128 tile / block (4 waves, each 64x64 via 4x4 of 16x16x32 MFMA), BK=64:
// 32 MFMA/wave per barrier-drain (2x the BK=32 work per vmcnt(0) stall), 64
// K-iterations instead of 128. LDS 32 KB -> still up to 5 blocks/CU.
// LDS rows are 64 bf16 = 128 B = 8 x 16B bank-groups; slot s = kseg ^ (row&7)
// makes every quad's ds_read_b128 hit each bank-group exactly 2x (2-way free).
// launch_bounds(256,4): squeeze unified VGPR+AGPR under 128 for 4 waves/SIMD.
__global__ __launch_bounds__(256, 4) void gemm_bt(const bf16* __restrict__ A,
                                                  const bf16* __restrict__ B,
                                                  float* __restrict__ C, int K,
                                                  int N) {
  __shared__ __align__(16) bf16 sA[128 * 64];
  __shared__ __align__(16) bf16 sB[128 * 64];
  int t = threadIdx.x;
  int m0 = blockIdx.y * 128, n0 = blockIdx.x * 128;
  int grow = t >> 3;                      // row within a 32-row staging chunk
  int gseg = (t & 7) ^ (grow & 7);        // swizzled global k-segment for slot
  const bf16* Ag = A + (size_t)(m0 + grow) * K + gseg * 8;
  const bf16* Bg = B + (size_t)(n0 + grow) * K + gseg * 8;
  bf16* lA = sA + t * 8;
  bf16* lB = sB + t * 8;
  size_t cstep = (size_t)32 * K;  // 32-row chunk stride (elements)

  int lane = t & 63, w = t >> 6;
  int quad = lane >> 4, lrow = lane & 15;
  int wm = (w >> 1) * 64, wn = (w & 1) * 64;
  int s0 = quad ^ (lrow & 7);             // de-swizzled k-group, half 0
  // half-1 group = s0 ^ 4 -> element delta = +-32
  int d1 = 32 - ((s0 & 4) << 4);
  const bf16* pA[4];
  const bf16* pB[4];
  #pragma unroll
  for (int i = 0; i < 4; i++) {
    pA[i] = sA + (wm + i * 16 + lrow) * 64 + s0 * 8;
    pB[i] = sB + (wn + i * 16 + lrow) * 64 + s0 * 8;
  }
  f32x4 acc[4][4];
  #pragma unroll
  for (int i = 0; i < 4; i++)
    #pragma unroll
    for (int j = 0; j < 4; j++) acc[i][j] = (f32x4)0.f;

  for (int k0 = 0; k0 < K; k0 += 64) {
    g2l16(Ag + k0, lA);
    g2l16(Ag + cstep + k0, lA + 2048);
    g2l16(Ag + 2 * cstep + k0, lA + 4096);
    g2l16(Ag + 3 * cstep + k0, lA + 6144);
    g2l16(Bg + k0, lB);
    g2l16(Bg + cstep + k0, lB + 2048);
    g2l16(Bg + 2 * cstep + k0, lB + 4096);
    g2l16(Bg + 3 * cstep + k0, lB + 6144);
    __syncthreads();  // waits vmcnt(0) -> staging complete
    #pragma unroll
    for (int h = 0; h < 2; h++) {
      int d = h ? d1 : 0;
      bf16x8 af[4], bfr[4];
      #pragma unroll
      for (int i = 0; i < 4; i++) af[i] = *(const bf16x8*)(pA[i] + d);
      #pragma unroll
      for (int j = 0; j < 4; j++) bfr[j] = *(const bf16x8*)(pB[j] + d);
      #pragma unroll
      for (int i = 0; i < 4; i++)
        #pragma unroll
        for (int j = 0; j < 4; j++)
          acc[i][j] = __builtin_amdgcn_mfma_f32_16x16x32_bf16(af[i], bfr[j],
                                                              acc[i][j], 0, 0, 0);
    }
    __syncthreads();
  }
  // C/D layout: n = lane&15, m = quad*4 + reg (m89/m91-verified mapping)
  #pragma unroll
  for (int i = 0; i < 4; i++) {
    #pragma unroll
    for (int r = 0; r < 4; r++) {
      int row = m0 + wm + i * 16 + quad * 4 + r;
      float* Cr = C + (size_t)row * N + n0 + wn + lrow;
      #pragma unroll
      for (int j = 0; j < 4; j++) Cr[j * 16] = acc[i][j][r];
    }
  }
}

// per-row: Smm=sum mx^2, Smy=sum mx*y -> scalars -> out = s*(A*mx + B*y)
// in-place on d_out. hardcoded for N == 4096.
__global__ __launch_bounds__(256) void finish(float* __restrict__ out,
                                              const float* __restrict__ y,
                                              const float* __restrict__ y2p,
                                              const float* __restrict__ q,
                                              int N) {
  int row = blockIdx.x, t = threadIdx.x;
  float4* orow = (float4*)(out + (size_t)row * N);
  const float4* yv = (const float4*)y;
  float smm = 0.f, smy = 0.f;
  float4 rm[4], ry[4];
  #pragma unroll
  for (int ii = 0; ii < 4; ii++) {
    float4 a = orow[ii * 256 + t];
    float4 b = yv[ii * 256 + t];
    rm[ii] = a;
    ry[ii] = b;
    smm += a.x * a.x + a.y * a.y + a.z * a.z + a.w * a.w;
    smy += a.x * b.x + a.y * b.y + a.z * b.z + a.w * b.w;
  }
  reduce2(smm, smy);
  float y2 = *y2p;  // = |y|^2
  float mxn = fmaxf(sqrtf(smm), MINN);
  float r = tanhf(mxn * q[row]);
  float alpha = (smm == 0.f) ? 0.f : r / mxn;  // res = alpha * mx
  float x2 = (smm == 0.f) ? 0.f : r * r;       // |res|^2
  float xy = alpha * smy;                      // <res, y>
  float c1 = 1.f + 2.f * xy + y2;
  float den = fmaxf(1.f + 2.f * xy + x2 * y2, MINN);
  float Af = c1 * alpha / den;
  float Bf = (1.f - x2) / den;
  // |o|^2 analytically: no second reduction needed
  float on2 = Af * Af * smm + 2.f * Af * Bf * smy + Bf * Bf * y2;
  float on = sqrtf(fmaxf(on2, 0.f));
  float s = (on > MAXNORM) ? MAXNORM / fmaxf(on, MINN) : 1.f;
  float As = Af * s, Bs = Bf * s;
  #pragma unroll
  for (int ii = 0; ii < 4; ii++) {
    float4 a = rm[ii], b = ry[ii];
    float4 o;
    o.x = As * a.x + Bs * b.x;
    o.y = As * a.y + Bs * b.y;
    o.z = As * a.z + Bs * b.z;
    o.w = As * a.w + Bs * b.w;
    orow[ii * 256 + t] = o;
  }
}

extern "C" void kernel_launch(void* const* d_in, const int* in_sizes, int n_in,
                              void* d_out, int out_size, void* d_ws,
                              size_t ws_size, hipStream_t stream) {
  const float* x = (const float*)d_in[0];
  const float* W = (const float*)d_in[1];
  const float* bias = (const float*)d_in[2];
  float* out = (float*)d_out;
  int OUT = in_sizes[2];
  int IN = in_sizes[1] / OUT;
  int Bm = in_sizes[0] / IN;

  // workspace carve: Xb (B*IN bf16) | Wb (OUT*IN bf16) | q (B f32) | y (OUT f32) | y2 (1 f32)
  char* ws = (char*)d_ws;
  size_t xb_bytes = (size_t)Bm * IN * sizeof(bf16);
  size_t wb_bytes = (size_t)OUT * IN * sizeof(bf16);
  bf16* Xb = (bf16*)ws;
  bf16* Wb = (bf16*)(ws + xb_bytes);
  float* q = (float*)(ws + xb_bytes + wb_bytes);
  float* y = q + Bm;
  float* y2 = y + OUT;

  long nw = (long)OUT * IN;
  int convBlocks = (int)((nw / 8 + 255) / 256);
  prep_all<<<convBlocks + Bm + 1, 256, 0, stream>>>(
      W, Wb, nw, convBlocks, x, Xb, q, IN, Bm, bias, y, y2, OUT);
  gemm_bt<<<dim3(OUT / 128, Bm / 128), 256, 0, stream>>>(Xb, Wb, out, IN, OUT);
  finish<<<Bm, 256, 0, stream>>>(out, y, y2, q, OUT);
}